// Round 3
// baseline (1474.516 us; speedup 1.0000x reference)
//
#include <hip/hip_runtime.h>
#include <hip/hip_bf16.h>
#include <cstdint>
#include <cstddef>

// SparseMoE MI355X gfx950. ALL I/O FP32 (reference dtype); bf16 MFMA internally.
// gate(top2 logits) -> tile list -> 4x [ffn1 chunk -> ffn2 chunk -> atomic into d_out].
// ws (~33.7 MB):
//   [0)       Hc    bf16 16384*1024*2 = 33554432
//   [33.5M)   list  16384*4
//   [+64K)    eids  8192*4
//   [+32K)    meta  counts/offsets/cursors/n_tiles/tile_e/tile_row0

#define TOKENS 8192
#define DM 1024
#define DH 4096
#define NE 8
#define CHUNK 1024
#define NCHUNK 4
#define MAXTILES 160

typedef __attribute__((ext_vector_type(8))) short short8;
typedef __attribute__((ext_vector_type(4))) float f32x4;
typedef unsigned short u16;
typedef unsigned int u32;

__device__ __forceinline__ u16 f2bf(float f) {
  u32 u = __builtin_bit_cast(u32, f);
  u += 0x7fffu + ((u >> 16) & 1u);  // RNE
  return (u16)(u >> 16);
}
__device__ __forceinline__ float bf2f(u16 u) {
  u32 v = ((u32)u) << 16;
  return __builtin_bit_cast(float, v);
}

// ---------------- gating: top-2 of fp32 logits (softmax monotone, gates > 0)
__global__ __launch_bounds__(256) void gate_topk(
    const float* __restrict__ x0, const float* __restrict__ Wg,
    int* __restrict__ eids, int* __restrict__ counts) {
  const int wave = threadIdx.x >> 6;
  const int lane = threadIdx.x & 63;
  const int t = blockIdx.x * 4 + wave;
  const float* xrow = x0 + (size_t)t * DM + lane * 16;
  float xs[16];
#pragma unroll
  for (int q = 0; q < 4; ++q) *(float4*)(xs + q * 4) = *(const float4*)(xrow + q * 4);
  float s[NE] = {0.f, 0.f, 0.f, 0.f, 0.f, 0.f, 0.f, 0.f};
#pragma unroll
  for (int j = 0; j < 16; ++j) {
    const float* wrow = Wg + (size_t)(lane * 16 + j) * NE;
    float w[8];
    *(float4*)(w) = *(const float4*)(wrow);
    *(float4*)(w + 4) = *(const float4*)(wrow + 4);
#pragma unroll
    for (int e = 0; e < NE; ++e) s[e] += xs[j] * w[e];
  }
#pragma unroll
  for (int off = 32; off > 0; off >>= 1)
#pragma unroll
    for (int e = 0; e < NE; ++e) s[e] += __shfl_down(s[e], off);
  if (lane == 0) {
    int a1 = 0; float v1 = s[0];
#pragma unroll
    for (int e = 1; e < NE; ++e) if (s[e] > v1) { v1 = s[e]; a1 = e; }  // first-index ties
    int a2 = -1; float v2 = 0.f; bool init = false;
#pragma unroll
    for (int e = 0; e < NE; ++e) {
      if (e == a1) continue;
      if (!init || s[e] > v2) { v2 = s[e]; a2 = e; init = true; }
    }
    eids[t] = a1 | (a2 << 8);
    atomicAdd(&counts[a1], 1);
    atomicAdd(&counts[a2], 1);
  }
}

// offsets/cursors + expert-pure 128-row tile list (nt <= 136 < MAXTILES)
__global__ void prefix_tiles(const int* __restrict__ counts, int* __restrict__ offsets,
                             int* __restrict__ cursors, int* __restrict__ n_tiles,
                             int* __restrict__ tile_e, int* __restrict__ tile_row0) {
  if (threadIdx.x != 0) return;
  int o = 0, nt = 0;
  for (int e = 0; e < NE; ++e) {
    offsets[e] = o; cursors[e] = o;
    for (int r = 0; r < counts[e]; r += 128) { tile_e[nt] = e; tile_row0[nt] = r; ++nt; }
    o += counts[e];
  }
  *n_tiles = nt;
}

__global__ __launch_bounds__(256) void scatter_tokens(
    const int* __restrict__ eids, int* __restrict__ cursors, int* __restrict__ list) {
  int t = blockIdx.x * 256 + threadIdx.x;
  if (t >= TOKENS) return;
  int p = eids[t];
  int s0 = atomicAdd(&cursors[p & 255], 1);
  list[s0] = t;
  int s1 = atomicAdd(&cursors[(p >> 8) & 255], 1);
  list[s1] = t;
}

// ---------------- ffn1 chunk: Hc[slot][n] = relu(xl[tok] @ W1[e][:, cbase+n] + b1)
// 128x128 tile, BK=64, 4 waves each 64x64 (4x4 of mfma 16x16x32 bf16).
__global__ __launch_bounds__(256) void ffn1_kernel(
    const float* __restrict__ xl, const float* __restrict__ W1,
    const float* __restrict__ b1, const int* __restrict__ list,
    const int* __restrict__ counts, const int* __restrict__ offsets,
    const int* __restrict__ n_tiles, const int* __restrict__ tile_e,
    const int* __restrict__ tile_row0, u16* __restrict__ Hc, int cbase) {
  const int ti = blockIdx.y;
  if (ti >= *n_tiles) return;
  const int e = tile_e[ti];
  const int row0 = tile_row0[ti];
  const int cnt = counts[e];
  const int off = offsets[e];
  const int n0 = blockIdx.x * 128;

  __shared__ u16 As[128 * 64];   // [row][k] bf16
  __shared__ u16 Bs[128 * 66];   // [n][k] bf16 transposed, stride 66

  const int tid = threadIdx.x;
  const int lane = tid & 63;
  const int wave = tid >> 6;

  const float* arow[4];
#pragma unroll
  for (int p = 0; p < 4; ++p) {
    int rr = row0 + p * 32 + (tid >> 3);
    if (rr >= cnt) rr = cnt - 1;      // clamp; stores guarded later
    int tok = list[off + rr];
    arow[p] = xl + (size_t)tok * DM + ((tid & 7) << 3);
  }
  const float* gB = W1 + (size_t)e * DM * DH + cbase + n0;
  const int k2 = (tid >> 4) * 2;
  const int ncol = (tid & 15) * 8;

  f32x4 acc[4][4];
#pragma unroll
  for (int mi = 0; mi < 4; ++mi)
#pragma unroll
    for (int ni = 0; ni < 4; ++ni) acc[mi][ni] = (f32x4){0.f, 0.f, 0.f, 0.f};

  const int wm = (wave & 1) * 64;
  const int wn = (wave >> 1) * 64;

  for (int k0 = 0; k0 < DM; k0 += 64) {
#pragma unroll
    for (int p = 0; p < 4; ++p) {    // A: fp32 -> bf16, lane-contiguous rows
      float4 v0 = *(const float4*)(arow[p] + k0);
      float4 v1 = *(const float4*)(arow[p] + k0 + 4);
      u16 h[8];
      h[0] = f2bf(v0.x); h[1] = f2bf(v0.y); h[2] = f2bf(v0.z); h[3] = f2bf(v0.w);
      h[4] = f2bf(v1.x); h[5] = f2bf(v1.y); h[6] = f2bf(v1.z); h[7] = f2bf(v1.w);
      *(uint4*)(&As[(p * 32 + (tid >> 3)) * 64 + ((tid & 7) << 3)]) = *(uint4*)h;
    }
#pragma unroll
    for (int p = 0; p < 2; ++p) {    // B: fp32 rows k,k+1 -> bf16 pairs, transposed
      int k = k2 + p * 32;
      const float* s0 = gB + (size_t)(k0 + k) * DH + ncol;
      const float* s1 = s0 + DH;
      float r0[8], r1[8];
      *(float4*)(r0) = *(const float4*)(s0);
      *(float4*)(r0 + 4) = *(const float4*)(s0 + 4);
      *(float4*)(r1) = *(const float4*)(s1);
      *(float4*)(r1 + 4) = *(const float4*)(s1 + 4);
#pragma unroll
      for (int j = 0; j < 8; ++j) {
        u32 w32 = (u32)f2bf(r0[j]) | ((u32)f2bf(r1[j]) << 16);
        *(u32*)(&Bs[(ncol + j) * 66 + k]) = w32;   // k even -> 4B aligned
      }
    }
    __syncthreads();
#pragma unroll
    for (int s = 0; s < 2; ++s) {
      const int kk = s * 32 + (lane >> 4) * 8;
      short8 af[4], bfr[4];
#pragma unroll
      for (int mi = 0; mi < 4; ++mi)
        af[mi] = *(const short8*)(&As[(wm + mi * 16 + (lane & 15)) * 64 + kk]);
#pragma unroll
      for (int ni = 0; ni < 4; ++ni) {
        const u32* bp = (const u32*)(&Bs[(wn + ni * 16 + (lane & 15)) * 66 + kk]);
        union { u32 u[4]; short8 v; } bu;
        bu.u[0] = bp[0]; bu.u[1] = bp[1]; bu.u[2] = bp[2]; bu.u[3] = bp[3];
        bfr[ni] = bu.v;
      }
#pragma unroll
      for (int mi = 0; mi < 4; ++mi)
#pragma unroll
        for (int ni = 0; ni < 4; ++ni)
          acc[mi][ni] = __builtin_amdgcn_mfma_f32_16x16x32_bf16(af[mi], bfr[ni], acc[mi][ni], 0, 0, 0);
    }
    __syncthreads();
  }

  float bb[4];
#pragma unroll
  for (int ni = 0; ni < 4; ++ni)
    bb[ni] = b1[e * DH + cbase + n0 + wn + ni * 16 + (lane & 15)];
#pragma unroll
  for (int mi = 0; mi < 4; ++mi) {
#pragma unroll
    for (int r = 0; r < 4; ++r) {
      int rrow = row0 + wm + mi * 16 + (lane >> 4) * 4 + r;
      if (rrow < cnt) {
        u16* h = Hc + (size_t)(off + rrow) * CHUNK + n0 + wn + (lane & 15);
#pragma unroll
        for (int ni = 0; ni < 4; ++ni) {
          float v = acc[mi][ni][r] + bb[ni];
          h[ni * 16] = f2bf(v > 0.f ? v : 0.f);
        }
      }
    }
  }
}

// ---------------- ffn2 chunk: d_out[tok][n] += Hc[slot] @ W2[e][cbase+k][n] (+b2 on c0)
__global__ __launch_bounds__(256) void ffn2_kernel(
    const u16* __restrict__ Hc, const float* __restrict__ W2,
    const float* __restrict__ b2, const int* __restrict__ list,
    const int* __restrict__ counts, const int* __restrict__ offsets,
    const int* __restrict__ n_tiles, const int* __restrict__ tile_e,
    const int* __restrict__ tile_row0, float* __restrict__ out, int cbase) {
  const int ti = blockIdx.y;
  if (ti >= *n_tiles) return;
  const int e = tile_e[ti];
  const int row0 = tile_row0[ti];
  const int cnt = counts[e];
  const int off = offsets[e];
  const int n0 = blockIdx.x * 128;

  __shared__ u16 As[128 * 64];
  __shared__ u16 Bs[128 * 66];

  const int tid = threadIdx.x;
  const int lane = tid & 63;
  const int wave = tid >> 6;

  const u16* arow[4];
#pragma unroll
  for (int p = 0; p < 4; ++p) {
    int rr = row0 + p * 32 + (tid >> 3);
    if (rr >= cnt) rr = cnt - 1;
    arow[p] = Hc + (size_t)(off + rr) * CHUNK + ((tid & 7) << 3);
  }
  const float* gB = W2 + (size_t)e * DH * DM + n0;
  const int k2 = (tid >> 4) * 2;
  const int ncol = (tid & 15) * 8;

  f32x4 acc[4][4];
#pragma unroll
  for (int mi = 0; mi < 4; ++mi)
#pragma unroll
    for (int ni = 0; ni < 4; ++ni) acc[mi][ni] = (f32x4){0.f, 0.f, 0.f, 0.f};

  const int wm = (wave & 1) * 64;
  const int wn = (wave >> 1) * 64;

  for (int k0 = 0; k0 < CHUNK; k0 += 64) {
#pragma unroll
    for (int p = 0; p < 4; ++p) {    // A: already bf16
      uint4 v = *(const uint4*)(arow[p] + k0);
      *(uint4*)(&As[(p * 32 + (tid >> 3)) * 64 + ((tid & 7) << 3)]) = v;
    }
#pragma unroll
    for (int p = 0; p < 2; ++p) {
      int k = k2 + p * 32;
      const float* s0 = gB + (size_t)(cbase + k0 + k) * DM + ncol;
      const float* s1 = s0 + DM;
      float r0[8], r1[8];
      *(float4*)(r0) = *(const float4*)(s0);
      *(float4*)(r0 + 4) = *(const float4*)(s0 + 4);
      *(float4*)(r1) = *(const float4*)(s1);
      *(float4*)(r1 + 4) = *(const float4*)(s1 + 4);
#pragma unroll
      for (int j = 0; j < 8; ++j) {
        u32 w32 = (u32)f2bf(r0[j]) | ((u32)f2bf(r1[j]) << 16);
        *(u32*)(&Bs[(ncol + j) * 66 + k]) = w32;
      }
    }
    __syncthreads();
#pragma unroll
    for (int s = 0; s < 2; ++s) {
      const int kk = s * 32 + (lane >> 4) * 8;
      short8 af[4], bfr[4];
#pragma unroll
      for (int mi = 0; mi < 4; ++mi)
        af[mi] = *(const short8*)(&As[(wm + mi * 16 + (lane & 15)) * 64 + kk]);
#pragma unroll
      for (int ni = 0; ni < 4; ++ni) {
        const u32* bp = (const u32*)(&Bs[(wn + ni * 16 + (lane & 15)) * 66 + kk]);
        union { u32 u[4]; short8 v; } bu;
        bu.u[0] = bp[0]; bu.u[1] = bp[1]; bu.u[2] = bp[2]; bu.u[3] = bp[3];
        bfr[ni] = bu.v;
      }
#pragma unroll
      for (int mi = 0; mi < 4; ++mi)
#pragma unroll
        for (int ni = 0; ni < 4; ++ni)
          acc[mi][ni] = __builtin_amdgcn_mfma_f32_16x16x32_bf16(af[mi], bfr[ni], acc[mi][ni], 0, 0, 0);
    }
    __syncthreads();
  }

  float bb[4];
#pragma unroll
  for (int ni = 0; ni < 4; ++ni)
    bb[ni] = (cbase == 0) ? b2[e * DM + n0 + wn + ni * 16 + (lane & 15)] : 0.f;
#pragma unroll
  for (int mi = 0; mi < 4; ++mi) {
#pragma unroll
    for (int r = 0; r < 4; ++r) {
      int rrow = row0 + wm + mi * 16 + (lane >> 4) * 4 + r;
      if (rrow < cnt) {
        int tok = list[off + rrow];
        float* ar = out + (size_t)tok * DM + n0 + wn + (lane & 15);
#pragma unroll
        for (int ni = 0; ni < 4; ++ni)
          atomicAdd(&ar[ni * 16], acc[mi][ni][r] + bb[ni]);
      }
    }
  }
}

extern "C" void kernel_launch(void* const* d_in, const int* in_sizes, int n_in,
                              void* d_out, int out_size, void* d_ws, size_t ws_size,
                              hipStream_t stream) {
  const float* xl = (const float*)d_in[0];
  const float* x0 = (const float*)d_in[1];
  const float* Wg = (const float*)d_in[2];
  const float* W1 = (const float*)d_in[3];
  const float* b1 = (const float*)d_in[4];
  const float* W2 = (const float*)d_in[5];
  const float* b2 = (const float*)d_in[6];
  float* out = (float*)d_out;

  char* ws = (char*)d_ws;
  u16* Hc   = (u16*)ws;                       // 33554432 B
  int* list = (int*)(ws + 33554432);          // 65536 B
  int* eids = (int*)(ws + 33619968);          // 32768 B
  int* meta = (int*)(ws + 33652736);
  int* counts    = meta;        // 8
  int* offsets   = meta + 8;    // 8
  int* cursors   = meta + 16;   // 8
  int* n_tiles   = meta + 24;   // 1
  int* tile_e    = meta + 32;   // MAXTILES
  int* tile_row0 = meta + 32 + MAXTILES;

  hipMemsetAsync(counts, 0, 8 * sizeof(int), stream);
  hipMemsetAsync(out, 0, (size_t)TOKENS * DM * sizeof(float), stream);

  gate_topk<<<TOKENS / 4, 256, 0, stream>>>(x0, Wg, eids, counts);
  prefix_tiles<<<1, 64, 0, stream>>>(counts, offsets, cursors, n_tiles, tile_e, tile_row0);
  scatter_tokens<<<TOKENS / 256, 256, 0, stream>>>(eids, cursors, list);

  for (int c = 0; c < NCHUNK; ++c) {
    ffn1_kernel<<<dim3(CHUNK / 128, MAXTILES), 256, 0, stream>>>(
        xl, W1, b1, list, counts, offsets, n_tiles, tile_e, tile_row0, Hc, c * CHUNK);
    ffn2_kernel<<<dim3(DM / 128, MAXTILES), 256, 0, stream>>>(
        Hc, W2, b2, list, counts, offsets, n_tiles, tile_e, tile_row0, out, c * CHUNK);
  }
}